// Round 1
// baseline (310.003 us; speedup 1.0000x reference)
//
#include <hip/hip_runtime.h>
#include <hip/hip_bf16.h>
#include <math.h>

#define B_  32
#define S_  512
#define D_  512
#define E_  8
#define H_  2048
#define O_  512

typedef __bf16 bf16x8 __attribute__((ext_vector_type(8)));
typedef float  f32x4  __attribute__((ext_vector_type(4)));

#define GL2LDS(src, dst) \
  __builtin_amdgcn_global_load_lds((const __attribute__((address_space(1))) void*)(src), \
                                   (__attribute__((address_space(3))) void*)(dst), 16, 0, 0)

__device__ __forceinline__ float gelu_exact(float v) {
  return 0.5f * v * (1.0f + erff(v * 0.70710678118654752f));
}

// ---------------- pooling + gating ----------------
__global__ __launch_bounds__(256) void pool_gate_kernel(
    const float* __restrict__ x, const float* __restrict__ attn_w,
    const float* __restrict__ attn_b, const float* __restrict__ gate_w,
    const float* __restrict__ gate_b, int* __restrict__ gidx, float* __restrict__ gwt)
{
  __shared__ float sc[512];
  __shared__ float pooled[512];
  __shared__ float red[8];
  const int tid = threadIdx.x;
  const int b = blockIdx.x;
  const float* xb = x + (size_t)b * S_ * D_;
  const float ab = attn_b[0];

  // scores[s] = x[b,s,:] . attn_w + attn_b
  for (int s = tid; s < S_; s += 256) {
    const float4* xr = (const float4*)(xb + (size_t)s * D_);
    const float4* wr = (const float4*)attn_w;
    float acc = 0.f;
    for (int i = 0; i < D_ / 4; ++i) {
      float4 xv = xr[i], wv = wr[i];
      acc += xv.x * wv.x + xv.y * wv.y + xv.z * wv.z + xv.w * wv.w;
    }
    sc[s] = acc + ab;
  }
  __syncthreads();

  // softmax over S=512
  float m = fmaxf(sc[tid], sc[tid + 256]);
  for (int off = 32; off; off >>= 1) m = fmaxf(m, __shfl_down(m, off));
  if ((tid & 63) == 0) red[tid >> 6] = m;
  __syncthreads();
  if (tid == 0) red[0] = fmaxf(fmaxf(red[0], red[1]), fmaxf(red[2], red[3]));
  __syncthreads();
  m = red[0];
  float e0 = expf(sc[tid] - m), e1 = expf(sc[tid + 256] - m);
  float ssum = e0 + e1;
  for (int off = 32; off; off >>= 1) ssum += __shfl_down(ssum, off);
  if ((tid & 63) == 0) red[4 + (tid >> 6)] = ssum;
  __syncthreads();
  if (tid == 0) red[4] = red[4] + red[5] + red[6] + red[7];
  __syncthreads();
  float inv = 1.f / red[4];
  sc[tid] = e0 * inv;
  sc[tid + 256] = e1 * inv;
  __syncthreads();

  // pooled[d] = sum_s aw[s] * x[b,s,d]
  float p0 = 0.f, p1 = 0.f;
  for (int s = 0; s < S_; ++s) {
    float awv = sc[s];
    p0 += awv * xb[(size_t)s * D_ + tid];
    p1 += awv * xb[(size_t)s * D_ + tid + 256];
  }
  pooled[tid] = p0;
  pooled[tid + 256] = p1;
  __syncthreads();

  // gates
  if (tid < E_) {
    float z = gate_b[tid];
    for (int d = 0; d < D_; ++d) z += pooled[d] * gate_w[d * E_ + tid];
    red[tid] = z;
  }
  __syncthreads();
  if (tid == 0) {
    float zmax = red[0];
    for (int i = 1; i < E_; ++i) zmax = fmaxf(zmax, red[i]);
    float ge[E_]; float zs = 0.f;
    for (int i = 0; i < E_; ++i) { ge[i] = expf(red[i] - zmax); zs += ge[i]; }
    for (int i = 0; i < E_; ++i) ge[i] /= zs;
    int i0 = 0;
    for (int i = 1; i < E_; ++i) if (ge[i] > ge[i0]) i0 = i;
    int i1 = -1;
    for (int i = 0; i < E_; ++i) if (i != i0 && (i1 < 0 || ge[i] > ge[i1])) i1 = i;
    float denom = ge[i0] + ge[i1] + 1e-9f;
    gidx[b * 2 + 0] = i0; gidx[b * 2 + 1] = i1;
    gwt[b * 2 + 0] = ge[i0] / denom; gwt[b * 2 + 1] = ge[i1] / denom;
  }
}

// ---------------- x -> bf16 ----------------
__global__ void cast_x_kernel(const float* __restrict__ in, ushort* __restrict__ outp, int n) {
  int i = blockIdx.x * blockDim.x + threadIdx.x;
  const int n4 = n >> 2;
  for (; i < n4; i += gridDim.x * blockDim.x) {
    float4 v = ((const float4*)in)[i];
    ushort4 o;
    o.x = __builtin_bit_cast(unsigned short, __float2bfloat16(v.x));
    o.y = __builtin_bit_cast(unsigned short, __float2bfloat16(v.y));
    o.z = __builtin_bit_cast(unsigned short, __float2bfloat16(v.z));
    o.w = __builtin_bit_cast(unsigned short, __float2bfloat16(v.w));
    ((ushort4*)outp)[i] = o;
  }
}

// ---------------- [z][R][C] f32 -> [z][C][R] bf16 ----------------
__global__ void transpose_cast_kernel(const float* __restrict__ in,
                                      __hip_bfloat16* __restrict__ outT, int R, int C)
{
  __shared__ float tile[32][33];
  const int z = blockIdx.z;
  const float* inz = in + (size_t)z * R * C;
  __hip_bfloat16* outz = outT + (size_t)z * R * C;
  const int c0 = blockIdx.x * 32, r0 = blockIdx.y * 32;
  const int tx = threadIdx.x, ty = threadIdx.y;
#pragma unroll
  for (int jj = 0; jj < 4; ++jj) {
    int r = r0 + ty + jj * 8;
    tile[ty + jj * 8][tx] = inz[(size_t)r * C + c0 + tx];
  }
  __syncthreads();
#pragma unroll
  for (int jj = 0; jj < 4; ++jj) {
    int c = c0 + ty + jj * 8;
    outz[(size_t)c * R + r0 + tx] = __float2bfloat16(tile[tx][ty + jj * 8]);
  }
}

// ---------------- GEMM core: C[128x128] += A[128xK] * B^T (B is [128 rows][K]) ----------------
// Both A and B tiles are k-contiguous (NT layout). LDS tile: [128 rows][64 k] bf16, linear,
// XOR-swizzle ((row&7)<<4) applied to the GLOBAL source and again on ds_read (involution).
__device__ __forceinline__ void stage_tile(char* lds, const __hip_bfloat16* g, int ldk, int kt, int tid) {
#pragma unroll
  for (int i = 0; i < 4; ++i) {
    int f = (i * 256 + tid) * 16;
    int row = f >> 7;
    int colb = (f & 127) ^ ((row & 7) << 4);
    const char* src = (const char*)g + ((size_t)row * ldk + kt) * 2 + colb;
    GL2LDS(src, lds + f);
  }
}

__device__ __forceinline__ void gemm_tiles(const __hip_bfloat16* Ag, const __hip_bfloat16* Bg,
                                           int K, char* As, char* Bs, f32x4 (&acc)[4][4])
{
  const int tid = threadIdx.x;
  const int l = tid & 63;
  const int w = tid >> 6;
  const int wm = (w >> 1) << 6;
  const int wn = (w & 1) << 6;
  const int lr = l & 15;
  const int kg = (l >> 4) << 3;
  for (int kt = 0; kt < K; kt += 64) {
    __syncthreads();
    stage_tile(As, Ag, K, kt, tid);
    stage_tile(Bs, Bg, K, kt, tid);
    __syncthreads();
#pragma unroll
    for (int kk = 0; kk < 2; ++kk) {
      const int kb = (kk * 32 + kg) * 2;
      bf16x8 af[4], bfv[4];
#pragma unroll
      for (int i = 0; i < 4; ++i) {
        int ra = wm + i * 16 + lr;
        af[i] = *(const bf16x8*)(As + ra * 128 + (kb ^ ((ra & 7) << 4)));
        int rb = wn + i * 16 + lr;
        bfv[i] = *(const bf16x8*)(Bs + rb * 128 + (kb ^ ((rb & 7) << 4)));
      }
#pragma unroll
      for (int mi = 0; mi < 4; ++mi)
#pragma unroll
        for (int ni = 0; ni < 4; ++ni)
          acc[mi][ni] = __builtin_amdgcn_mfma_f32_16x16x32_bf16(af[mi], bfv[ni], acc[mi][ni], 0, 0, 0);
    }
  }
}

// ---------------- GEMM1: H = gelu(x @ w1 + b1) ----------------
__global__ __launch_bounds__(256, 2) void gemm1_kernel(
    const __hip_bfloat16* __restrict__ Xb, const __hip_bfloat16* __restrict__ W1T,
    const float* __restrict__ b1, __hip_bfloat16* __restrict__ Hbuf,
    const int* __restrict__ gidx, int p0)
{
  __shared__ char lds[32768];
  char* As = lds; char* Bs = lds + 16384;
  const int p = p0 + blockIdx.y;
  const int b = p >> 1;
  const int e = gidx[p];
  const int s0 = (blockIdx.x >> 4) * 128;
  const int h0 = (blockIdx.x & 15) * 128;
  const __hip_bfloat16* Ag = Xb + ((size_t)b * S_ + s0) * D_;
  const __hip_bfloat16* Bg = W1T + ((size_t)e * H_ + h0) * D_;
  f32x4 acc[4][4] = {};
  gemm_tiles(Ag, Bg, D_, As, Bs, acc);

  const int tid = threadIdx.x, l = tid & 63, w = tid >> 6;
  const int wm = (w >> 1) << 6, wn = (w & 1) << 6;
  const int r4 = (l >> 4) << 2, cc = l & 15;
  const float* b1e = b1 + (size_t)e * H_ + h0;
  __hip_bfloat16* Hb = Hbuf + ((size_t)blockIdx.y * S_ + s0) * H_ + h0;
#pragma unroll
  for (int mi = 0; mi < 4; ++mi) {
    int row = wm + mi * 16 + r4;
#pragma unroll
    for (int ni = 0; ni < 4; ++ni) {
      int col = wn + ni * 16 + cc;
      float bias = b1e[col];
      __hip_bfloat16* dst = Hb + (size_t)row * H_ + col;
#pragma unroll
      for (int j = 0; j < 4; ++j) {
        float v = gelu_exact(acc[mi][ni][j] + bias);
        dst[(size_t)j * H_] = __float2bfloat16(v);
      }
    }
  }
}

// ---------------- GEMM2: out += g * gelu(H @ w2 + b2) ----------------
__global__ __launch_bounds__(256, 2) void gemm2_kernel(
    const __hip_bfloat16* __restrict__ Hbuf, const __hip_bfloat16* __restrict__ W2T,
    const float* __restrict__ b2, float* __restrict__ out,
    const int* __restrict__ gidx, const float* __restrict__ gwt, int p0)
{
  __shared__ char lds[32768];
  char* As = lds; char* Bs = lds + 16384;
  const int p = p0 + blockIdx.y;
  const int b = p >> 1;
  const int e = gidx[p];
  const float gw = gwt[p];
  const int s0 = (blockIdx.x >> 2) * 128;
  const int o0 = (blockIdx.x & 3) * 128;
  const __hip_bfloat16* Ag = Hbuf + ((size_t)blockIdx.y * S_ + s0) * H_;
  const __hip_bfloat16* Bg = W2T + ((size_t)e * O_ + o0) * H_;
  f32x4 acc[4][4] = {};
  gemm_tiles(Ag, Bg, H_, As, Bs, acc);

  const int tid = threadIdx.x, l = tid & 63, w = tid >> 6;
  const int wm = (w >> 1) << 6, wn = (w & 1) << 6;
  const int r4 = (l >> 4) << 2, cc = l & 15;
  const float* b2e = b2 + (size_t)e * O_ + o0;
  float* ob = out + ((size_t)b * S_ + s0) * O_ + o0;
#pragma unroll
  for (int mi = 0; mi < 4; ++mi) {
    int row = wm + mi * 16 + r4;
#pragma unroll
    for (int ni = 0; ni < 4; ++ni) {
      int col = wn + ni * 16 + cc;
      float bias = b2e[col];
      float* dst = ob + (size_t)row * O_ + col;
#pragma unroll
      for (int j = 0; j < 4; ++j) {
        float v = gelu_exact(acc[mi][ni][j] + bias) * gw;
        atomicAdd(dst + (size_t)j * O_, v);
      }
    }
  }
}

// ---------------- sentinel (ws too small signal) ----------------
__global__ void sentinel_kernel(float* out, int n) {
  int i = blockIdx.x * blockDim.x + threadIdx.x;
  for (; i < n; i += gridDim.x * blockDim.x) out[i] = 1.0e6f;
}

extern "C" void kernel_launch(void* const* d_in, const int* in_sizes, int n_in,
                              void* d_out, int out_size, void* d_ws, size_t ws_size,
                              hipStream_t stream)
{
  const float* x      = (const float*)d_in[0];
  const float* attn_w = (const float*)d_in[1];
  const float* attn_b = (const float*)d_in[2];
  const float* gate_w = (const float*)d_in[3];
  const float* gate_b = (const float*)d_in[4];
  const float* w1     = (const float*)d_in[5];
  const float* b1     = (const float*)d_in[6];
  const float* w2     = (const float*)d_in[7];
  const float* b2     = (const float*)d_in[8];
  float* out = (float*)d_out;

  char* ws = (char*)d_ws;
  const size_t OFF_GIDX = 0;
  const size_t OFF_GWT  = 256;
  const size_t OFF_X    = 512;
  const size_t SZ_X     = (size_t)B_ * S_ * D_ * 2;   // 16 MB
  const size_t OFF_W1T  = OFF_X + SZ_X;
  const size_t SZ_W1T   = (size_t)E_ * H_ * D_ * 2;   // 16 MB
  const size_t OFF_W2T  = OFF_W1T + SZ_W1T;
  const size_t SZ_W2T   = (size_t)E_ * O_ * H_ * 2;   // 16 MB
  const size_t OFF_H    = OFF_W2T + SZ_W2T;
  const size_t PAIR_H   = (size_t)S_ * H_ * 2;        // 2 MB per (b,slot) pair

  int G = 64;  // pairs per group (H-buffer sized G*2MB)
  while (G > 1 && OFF_H + (size_t)G * PAIR_H > ws_size) G >>= 1;
  if (OFF_H + (size_t)G * PAIR_H > ws_size) {
    hipLaunchKernelGGL(sentinel_kernel, dim3(256), dim3(256), 0, stream, out, out_size);
    return;
  }

  int*   gidx = (int*)(ws + OFF_GIDX);
  float* gwt  = (float*)(ws + OFF_GWT);
  __hip_bfloat16* xb   = (__hip_bfloat16*)(ws + OFF_X);
  __hip_bfloat16* w1T  = (__hip_bfloat16*)(ws + OFF_W1T);
  __hip_bfloat16* w2T  = (__hip_bfloat16*)(ws + OFF_W2T);
  __hip_bfloat16* Hbuf = (__hip_bfloat16*)(ws + OFF_H);

  hipLaunchKernelGGL(pool_gate_kernel, dim3(B_), dim3(256), 0, stream,
                     x, attn_w, attn_b, gate_w, gate_b, gidx, gwt);
  hipLaunchKernelGGL(cast_x_kernel, dim3(2048), dim3(256), 0, stream,
                     x, (ushort*)xb, B_ * S_ * D_);
  hipLaunchKernelGGL(transpose_cast_kernel, dim3(H_ / 32, D_ / 32, E_), dim3(32, 8), 0, stream,
                     w1, w1T, D_, H_);
  hipLaunchKernelGGL(transpose_cast_kernel, dim3(O_ / 32, H_ / 32, E_), dim3(32, 8), 0, stream,
                     w2, w2T, H_, O_);
  hipMemsetAsync(d_out, 0, (size_t)out_size * sizeof(float), stream);

  for (int p0 = 0; p0 < B_ * 2; p0 += G) {
    hipLaunchKernelGGL(gemm1_kernel, dim3(64, G), dim3(256), 0, stream,
                       xb, w1T, b1, Hbuf, gidx, p0);
    hipLaunchKernelGGL(gemm2_kernel, dim3(16, G), dim3(256), 0, stream,
                       Hbuf, w2T, b2, out, gidx, gwt, p0);
  }
}